// Round 1
// 903.656 us; speedup vs baseline: 1.0215x; 1.0215x over previous
//
#include <hip/hip_runtime.h>

using u32 = unsigned int;

constexpr int B = 131072;
constexpr int K = 512;
constexpr int D = 128;
constexpr int RPB = 64;       // rows per block
constexpr int RG  = 8;        // rows per group
constexpr int NG  = RPB / RG; // groups per block
constexpr float SMBETA = 10.0f;

// flat f32-element offsets into d_out (return order)
constexpr size_t OFF_Q    = 0;
constexpr size_t OFF_VQ   = (size_t)B * D;            // 16777216
constexpr size_t OFF_ENT  = OFF_VQ + 1;               // 16777217
constexpr size_t OFF_INDS = OFF_VQ + 2;               // 16777218
constexpr size_t OFF_SOFT = OFF_INDS + (size_t)B;     // 16908290
constexpr size_t OFF_CL   = OFF_SOFT + (size_t)B * K; // 84017154

__global__ __launch_bounds__(512) void vq_main(
    const float* __restrict__ X, const float* __restrict__ E,
    float* __restrict__ out,
    u32* __restrict__ counts,
    float* __restrict__ sse_g, float* __restrict__ clus_g)
{
  __shared__ float gbuf[RG][K];   // 16 KiB: d values, then p~ values
  __shared__ float sx_sh[RG];
  __shared__ float m_sh[RG];
  __shared__ int   amin_sh[RG];
  __shared__ float invS_sh[RG];
  __shared__ float red_sh[16];

  const int tid  = threadIdx.x;
  const int j    = tid;          // code index, 0..511
  const int w    = tid >> 6;     // wave id 0..7
  const int lane = tid & 63;
  const int row0 = blockIdx.x * RPB;

  // ---- hoist Ej into VGPRs once (was: re-read 512B/thread per group,
  // 64-line-divergent vector loads that saturated the VMEM pipe) ----
  const float4* Ej4 = (const float4*)(E + (size_t)j * D);
  float4 ereg[32];               // 128 VGPRs; all indexing below is static
  #pragma unroll
  for (int s = 0; s < 32; ++s) ereg[s] = Ej4[s];

  // se_j = f32(sum_f64(f32(e*e))), strictly d-ascending — bit-identical to the
  // previous scalar loop (x,y,z,w order == d order).
  double seD = 0.0;
  #pragma unroll
  for (int s = 0; s < 32; ++s) {
    float e0 = ereg[s].x; seD += (double)(e0 * e0);
    float e1 = ereg[s].y; seD += (double)(e1 * e1);
    float e2 = ereg[s].z; seD += (double)(e2 * e2);
    float e3 = ereg[s].w; seD += (double)(e3 * e3);
  }
  const float se = (float)seD;

  float sse_l = 0.f, msum_l = 0.f;

  #pragma unroll 1
  for (int gi = 0; gi < NG; ++gi) {
    const int grow0 = row0 + gi * RG;

    // sx for the 8 rows of this group: wave w reduces row w (f32 squares, f64 sum, RN f32).
    {
      const float* xr = X + (size_t)(grow0 + w) * D;
      float v0 = xr[lane], v1 = xr[lane + 64];
      float s0 = v0 * v0, s1 = v1 * v1;
      double t = (double)s0 + (double)s1;
      for (int mk = 1; mk < 64; mk <<= 1) t += __shfl_xor(t, mk, 64);
      if (lane == 0) sx_sh[w] = (float)t;
    }
    __syncthreads();

    // dot(x_r, e_j): single f32 accumulator, sequential FMA over d ascending —
    // replicates BLAS sgemm micro-kernel accumulation (FMA, k-sequential).
    // x loads are block-uniform -> scalar (s_load) path; e comes from VGPRs.
    const float4* xg4 = (const float4*)(X + (size_t)grow0 * D);  // block-uniform
    float acc[RG];
    #pragma unroll
    for (int r = 0; r < RG; ++r) acc[r] = 0.f;

    #pragma unroll
    for (int s = 0; s < 32; ++s) {
      float4 e4 = ereg[s];
      #pragma unroll
      for (int r = 0; r < RG; ++r) {
        float4 x4 = xg4[r * 32 + s];
        float a = acc[r];
        a = fmaf(e4.x, x4.x, a);   // ascending d order, strictly sequential
        a = fmaf(e4.y, x4.y, a);
        a = fmaf(e4.z, x4.z, a);
        a = fmaf(e4.w, x4.w, a);
        acc[r] = a;
      }
    }

    // dist = RN(RN(sx + se) - 2*dot): exact replication of np's elementwise f32 ops
    float dq[RG];
    #pragma unroll
    for (int r = 0; r < RG; ++r) {
      float a = sx_sh[r] + se;
      dq[r] = a - 2.0f * acc[r];
      gbuf[r][j] = dq[r];
    }
    __syncthreads();

    // argmin over quantized dist, FIRST-index tie-break (np.argmin semantics)
    {
      float mv = 3.4e38f; int mi = 0;
      #pragma unroll
      for (int k2 = 0; k2 < 8; ++k2) {
        int jj = lane + 64 * k2;
        float v = gbuf[w][jj];
        if (v < mv || (v == mv && jj < mi)) { mv = v; mi = jj; }
      }
      for (int mk = 1; mk < 64; mk <<= 1) {
        float ov = __shfl_xor(mv, mk, 64);
        int   oi = __shfl_xor(mi, mk, 64);
        if (ov < mv || (ov == mv && oi < mi)) { mv = ov; mi = oi; }
      }
      if (lane == 0) { m_sh[w] = mv; amin_sh[w] = mi; }
    }
    __syncthreads();

    // softmax(-beta * dist), shift-invariant with the row min
    float p[RG];
    #pragma unroll
    for (int r = 0; r < RG; ++r) {
      p[r] = __expf(-SMBETA * (dq[r] - m_sh[r]));
      gbuf[r][j] = p[r];           // safe: d-values consumed before previous barrier
    }
    __syncthreads();

    // row-sum of p~: wave w reduces row w
    {
      float sv = 0.f;
      #pragma unroll
      for (int k2 = 0; k2 < 8; ++k2) sv += gbuf[w][lane + 64 * k2];
      for (int mk = 1; mk < 64; mk <<= 1) sv += __shfl_xor(sv, mk, 64);
      if (lane == 0) invS_sh[w] = 1.f / sv;
    }
    __syncthreads();

    // soft outputs (f32)
    #pragma unroll
    for (int r = 0; r < RG; ++r) {
      size_t row = (size_t)(grow0 + r);
      out[OFF_SOFT + row * K + j] = p[r] * invS_sh[r];
    }

    // per-row outputs: wave w handles row w
    {
      int row = grow0 + w;
      int am  = amin_sh[w];
      const float* xr = X + (size_t)row * D;
      const float* er = E + (size_t)am * D;
      #pragma unroll
      for (int t = 0; t < 2; ++t) {
        int d = lane + 64 * t;
        float xv = xr[d], ev = er[d];
        float df = ev - xv;
        sse_l = fmaf(df, df, sse_l);
        out[OFF_Q + (size_t)row * D + d] = ev;   // bit-exact f32 passthrough of emb row
      }
      if (lane == 0) {
        out[OFF_INDS + row] = (float)am;
        atomicAdd(&counts[am], 1u);
        msum_l += m_sh[w];    // quantized min == ref's dist at argmin (bit-exact)
      }
    }
    __syncthreads();
  }

  // block-reduce loss/cluster partials, one atomic each per block
  for (int mk = 1; mk < 64; mk <<= 1) {
    sse_l  += __shfl_xor(sse_l,  mk, 64);
    msum_l += __shfl_xor(msum_l, mk, 64);
  }
  if (lane == 0) { red_sh[w] = sse_l; red_sh[8 + w] = msum_l; }
  __syncthreads();
  if (tid == 0) {
    float s1 = 0.f, s2 = 0.f;
    for (int q = 0; q < 8; ++q) { s1 += red_sh[q]; s2 += red_sh[8 + q]; }
    atomicAdd(sse_g, s1);
    atomicAdd(clus_g, s2);
  }
}

__global__ __launch_bounds__(512) void vq_final(
    const u32* __restrict__ counts,
    const float* __restrict__ sse_g, const float* __restrict__ clus_g,
    float* __restrict__ out)
{
  __shared__ double part[8];
  const int tid = threadIdx.x, w = tid >> 6, lane = tid & 63;
  double pv = (double)counts[tid] / (double)B;
  double term = -pv * log(pv + 1e-10);
  for (int mk = 1; mk < 64; mk <<= 1) term += __shfl_xor(term, mk, 64);
  if (lane == 0) part[w] = term;
  __syncthreads();
  if (tid == 0) {
    double ent = 0.0;
    for (int q = 0; q < 8; ++q) ent += part[q];
    double sse = (double)*sse_g;
    double vq  = 1.25 * sse / ((double)B * (double)D);  // 0.25*commit + embed (same fwd value)
    double cl  = (double)*clus_g / (double)B;
    out[OFF_VQ]  = (float)vq;
    out[OFF_ENT] = (float)ent;
    out[OFF_CL]  = (float)cl;
  }
}

extern "C" void kernel_launch(void* const* d_in, const int* in_sizes, int n_in,
                              void* d_out, int out_size, void* d_ws, size_t ws_size,
                              hipStream_t stream) {
  const float* X = (const float*)d_in[0];   // latents [131072,128] f32
  const float* E = (const float*)d_in[1];   // emb_weight [512,128] f32
  if (n_in >= 2 && in_sizes[0] == K * D && in_sizes[1] == B * D) {
    const float* t = X; X = E; E = t;       // defensive: inputs swapped
  }
  float* out = (float*)d_out;

  u32*   counts = (u32*)d_ws;                    // 512 * u32
  float* sse_g  = (float*)((char*)d_ws + 2048);
  float* clus_g = (float*)((char*)d_ws + 2052);

  hipMemsetAsync(d_ws, 0, 4096, stream);
  vq_main<<<B / RPB, 512, 0, stream>>>(X, E, out, counts, sse_g, clus_g);
  vq_final<<<1, 512, 0, stream>>>(counts, sse_g, clus_g, out);
}